// Round 8
// baseline (127.576 us; speedup 1.0000x reference)
//
#include <hip/hip_runtime.h>
#include <math.h>

// out = softmax((Q .* K^T) / 64 .* V, axis=1)   (elementwise, NOT matmul)
// Q: [8192,4096] f32; K: [4096,8192] f32 (need K[j][i]); V,O: [8192,4096].
//
// R8: R7's barrier-free streaming + 2 blocks/CU. K band split into two
// 2048-col halves -> LDS 8x2052x4 = 65,664 B -> two 8-wave blocks resident
// (16 waves/CU vs R7's 8). Half-1 K loads issued into spare reg batches
// DURING half-0 streaming; at the mid barrier they are already in
// flight -> no exposed staging latency. 3 lgkm-only barriers total (no
// vmcnt drain; T4). Payload in 16 NAMED float4 (arrays spill: R1/R2).
// launch_bounds(512,4) caps VGPR at 128 = exactly 2-block residency
// (budget ~116; watch WRITE_SIZE for spill). No max-subtract: |x|<~1.5.

static constexpr int NROW = 8192;
static constexpr int D    = 4096;
static constexpr int RPB  = 8;           // rows per block == waves per block
static constexpr int HALF = 2048;        // K columns per LDS residency
static constexpr int LSTR = HALF + 4;    // 2052 dwords: banks spread, f4-aligned
static constexpr int NT   = 16;          // 16 tiles of 256 columns

#define LDS_BARRIER() asm volatile("s_waitcnt lgkmcnt(0)\n\ts_barrier" ::: "memory")

__global__ __launch_bounds__(512, 4)     // 4 waves/EU = 16 waves/CU = 2 blocks
void sdp_softmax_kernel(const float* __restrict__ Q,
                        const float* __restrict__ K,
                        const float* __restrict__ V,
                        float* __restrict__ O)
{
    __shared__ float ldsK[RPB * LSTR];   // 65,664 B -> 2 blocks/CU

    const int tid  = threadIdx.x;
    const int wv   = tid >> 6;           // wave id = local row (0..7)
    const int lane = tid & 63;

    // XCD-chunked swizzle (1024 % 8 == 0, bijective)
    const int nwg = gridDim.x;           // 1024
    const int cpx = nwg >> 3;            // 128
    const int hb  = blockIdx.x;
    const int lb  = (hb & 7) * cpx + (hb >> 3);

    const int row0 = lb * RPB;
    const int r    = row0 + wv;

    const float* qrow = Q + (size_t)r * D;
    const float* vrow = V + (size_t)r * D;
    float*       orow = O + (size_t)r * D;

    // K staging: thread (il=tid&7, jg=tid>>3) loads K[j0+8*jg+m][row0+il],
    // m=0..7. Per instr: 8 contiguous-lane groups of 32B; neighbor block
    // (rows +-8, same XCD via swizzle) consumes the other line half in L2.
    const int il = tid & 7;
    const int jg = tid >> 3;             // 0..63
    const float* kbase = K + (size_t)(8 * jg) * NROW + (size_t)row0 + il;
    const float scl = 0.015625f;         // 1/64 exact

    float sa0, sa1, sa2, sa3, sa4, sa5, sa6, sa7;
    float sb0, sb1, sb2, sb3, sb4, sb5, sb6, sb7;
    float sc0, sc1, sc2, sc3, sc4, sc5, sc6, sc7;
    float sd0, sd1, sd2, sd3, sd4, sd5, sd6, sd7;

#define LOADB(R, J0)                                                          \
    {                                                                         \
        const float* p = kbase + (size_t)(J0) * NROW;                         \
        R##0 = p[0];                  R##1 = p[NROW];                         \
        R##2 = p[2 * (size_t)NROW];   R##3 = p[3 * (size_t)NROW];             \
        R##4 = p[4 * (size_t)NROW];   R##5 = p[5 * (size_t)NROW];             \
        R##6 = p[6 * (size_t)NROW];   R##7 = p[7 * (size_t)NROW];             \
    }
#define WRITEB(R, COL)                                                        \
    {                                                                         \
        float* w = &ldsK[il * LSTR + (COL) + 8 * jg];                         \
        *(float4*)w       = make_float4(R##0, R##1, R##2, R##3);              \
        *(float4*)(w + 4) = make_float4(R##4, R##5, R##6, R##7);              \
    }

    // ---- half-0 staging (j 0..2047), 2-deep pipeline ----
    LOADB(sa, 0)
    // Q/V prologue: slots <- tiles 0..3 (in flight through staging+barrier)
    float4 qP0 = *(const float4*)(qrow + 0 * 256 + 4 * lane);
    float4 vP0 = *(const float4*)(vrow + 0 * 256 + 4 * lane);
    float4 qP1 = *(const float4*)(qrow + 1 * 256 + 4 * lane);
    float4 vP1 = *(const float4*)(vrow + 1 * 256 + 4 * lane);
    float4 qP2 = *(const float4*)(qrow + 2 * 256 + 4 * lane);
    float4 vP2 = *(const float4*)(vrow + 2 * 256 + 4 * lane);
    float4 qP3 = *(const float4*)(qrow + 3 * 256 + 4 * lane);
    float4 vP3 = *(const float4*)(vrow + 3 * 256 + 4 * lane);

    LOADB(sb, 512)   WRITEB(sa, 0)
    LOADB(sa, 1024)  WRITEB(sb, 512)
    LOADB(sb, 1536)  WRITEB(sa, 1024)
    WRITEB(sb, 1536)

    LDS_BARRIER();   // barrier 1: half-0 staged (Q/V loads stay in flight)

    float4 e0, e1, e2, e3, e4, e5, e6, e7,
           e8, e9, e10, e11, e12, e13, e14, e15;
    float s = 0.0f;

    // Body t: issue Q/V refill (tile t+4 -> slot t%4) first, then ds_read
    // kf, then exp+sum. No barriers inside. kf col = (t&7)*256.
#define BODY(t, ET, QS, VS)                                                   \
    {                                                                         \
        const float4 qc = QS, vc = VS;                                        \
        if ((t) + 4 < NT) {                                                   \
            QS = *(const float4*)(qrow + ((t) + 4) * 256 + 4 * lane);         \
            VS = *(const float4*)(vrow + ((t) + 4) * 256 + 4 * lane);         \
        }                                                                     \
        const float4 kf =                                                     \
            *(const float4*)&ldsK[wv * LSTR + ((t) & 7) * 256 + 4 * lane];    \
        ET.x = __expf(((qc.x * kf.x) * scl) * vc.x);                          \
        ET.y = __expf(((qc.y * kf.y) * scl) * vc.y);                          \
        ET.z = __expf(((qc.z * kf.z) * scl) * vc.z);                          \
        ET.w = __expf(((qc.w * kf.w) * scl) * vc.w);                          \
        s += ((ET.x + ET.y) + (ET.z + ET.w));                                 \
        __builtin_amdgcn_sched_barrier(0);                                    \
    }

    BODY(0,  e0,  qP0, vP0)
    BODY(1,  e1,  qP1, vP1)
    BODY(2,  e2,  qP2, vP2)
    LOADB(sa, 2048)                       // half-1 staging, issued early
    BODY(3,  e3,  qP3, vP3)
    BODY(4,  e4,  qP0, vP0)
    LOADB(sb, 2560)
    BODY(5,  e5,  qP1, vP1)
    BODY(6,  e6,  qP2, vP2)
    LOADB(sc, 3072)
    BODY(7,  e7,  qP3, vP3)
    LOADB(sd, 3584)

    LDS_BARRIER();   // barrier 2: all waves done READING half-0
    WRITEB(sa, 0)    // j 2048.. -> col 0   (loads long since / nearly done)
    WRITEB(sb, 512)
    WRITEB(sc, 1024)
    WRITEB(sd, 1536)
    LDS_BARRIER();   // barrier 3: half-1 staged

    BODY(8,  e8,  qP0, vP0)
    BODY(9,  e9,  qP1, vP1)
    BODY(10, e10, qP2, vP2)
    BODY(11, e11, qP3, vP3)
    BODY(12, e12, qP0, vP0)
    BODY(13, e13, qP1, vP1)
    BODY(14, e14, qP2, vP2)
    BODY(15, e15, qP3, vP3)
#undef BODY
#undef LOADB
#undef WRITEB

    // row sum (row == wave): butterfly across 64 lanes
    #pragma unroll
    for (int i = 1; i < 64; i <<= 1)
        s += __shfl_xor(s, i, 64);
    const float inv = 1.0f / s;

#define WRITE_TILE(t, ET)                                                     \
    {                                                                         \
        float4 xx = ET;                                                       \
        xx.x *= inv; xx.y *= inv; xx.z *= inv; xx.w *= inv;                   \
        *(float4*)(orow + (size_t)(t) * 256 + 4 * lane) = xx;                 \
    }

    WRITE_TILE(0,  e0)  WRITE_TILE(1,  e1)  WRITE_TILE(2,  e2)  WRITE_TILE(3,  e3)
    WRITE_TILE(4,  e4)  WRITE_TILE(5,  e5)  WRITE_TILE(6,  e6)  WRITE_TILE(7,  e7)
    WRITE_TILE(8,  e8)  WRITE_TILE(9,  e9)  WRITE_TILE(10, e10) WRITE_TILE(11, e11)
    WRITE_TILE(12, e12) WRITE_TILE(13, e13) WRITE_TILE(14, e14) WRITE_TILE(15, e15)
#undef WRITE_TILE
}

extern "C" void kernel_launch(void* const* d_in, const int* in_sizes, int n_in,
                              void* d_out, int out_size, void* d_ws, size_t ws_size,
                              hipStream_t stream) {
    const float* Q = (const float*)d_in[0];
    const float* K = (const float*)d_in[1];
    const float* V = (const float*)d_in[2];
    float* O = (float*)d_out;

    dim3 grid(NROW / RPB);   // 1024 blocks
    dim3 block(512);         // 8 waves
    sdp_softmax_kernel<<<grid, block, 0, stream>>>(Q, K, V, O);
}